// Round 10
// baseline (219.709 us; speedup 1.0000x reference)
//
#include <hip/hip_runtime.h>

#define NB 32
#define NN 256
#define DD 64
#define SROW 68          // LDS row stride (floats); b128-friendly, ~0 conflicts measured
#define TPAD 17          // transpose scratch row stride
#define FMAXV 3.402823466e+38f

// R16: R13/R15 skeleton (best: 117.5 = ~78us fixed window + ~39.6us kernel).
// R10-R15 all fed weights through SMEM (s_load): pass-split kk-loops
// (VGPR=32 = h16+acc16), lgkmcnt(0) full drains, and a >16KB-per-CU weight
// working set thrashing the scalar K$ -> ~34% VALU eff, kernel pinned at
// ~40us. Fix: force the weight stream onto the VMEM pipe via a runtime-0
// VGPR-pinned address offset (asm "+v") -> global_load_dwordx4 with vmcnt
// pipelining + L1 broadcast (uniform address = 1 line/instr). h stays
// LDS-hoisted + reg-pinned (R15); DS and VMEM now on separate counters.
// kc-chunks fully unrolled so loads hoist across chunks.

__device__ __forceinline__ void conv_full(
    const float* Hs, int n, int d0, const float* __restrict__ We, int voff,
    float ti[16], float tj[16])
{
#pragma unroll
    for (int j = 0; j < 16; ++j) { ti[j] = 0.f; tj[j] = 0.f; }
    const float* hrow  = Hs + (size_t)n * SROW;
    const float* wbase = We + d0 + voff;     // voff==0 but VGPR-resident -> VMEM
#pragma unroll
    for (int kc = 0; kc < 4; ++kc) {         // FULL unroll: loads hoist across chunks
        float h[16];
#pragma unroll
        for (int q = 0; q < 4; ++q) {
            float4 hv = *(const float4*)(hrow + kc * 16 + 4 * q);
            h[4*q+0] = hv.x; h[4*q+1] = hv.y; h[4*q+2] = hv.z; h[4*q+3] = hv.w;
        }
        // PIN: h becomes opaque VGPRs -- no LDS re-read / remat
#pragma unroll
        for (int q = 0; q < 16; ++q) asm volatile("" : "+v"(h[q]));
#pragma unroll
        for (int kk = 0; kk < 16; ++kk) {    // static h[] index
            const int k = kc * 16 + kk;
            const float hk = h[kk];
            const float* wi = wbase + (size_t)k * DD;          // global_load_dwordx4
            const float* wj = wbase + (size_t)(DD + k) * DD;   // global_load_dwordx4
#pragma unroll
            for (int q = 0; q < 4; ++q) {
                float4 a = *(const float4*)(wi + 4 * q);
                float4 c = *(const float4*)(wj + 4 * q);
                ti[4*q+0] = fmaf(hk, a.x, ti[4*q+0]);
                ti[4*q+1] = fmaf(hk, a.y, ti[4*q+1]);
                ti[4*q+2] = fmaf(hk, a.z, ti[4*q+2]);
                ti[4*q+3] = fmaf(hk, a.w, ti[4*q+3]);
                tj[4*q+0] = fmaf(hk, c.x, tj[4*q+0]);
                tj[4*q+1] = fmaf(hk, c.y, tj[4*q+1]);
                tj[4*q+2] = fmaf(hk, c.z, tj[4*q+2]);
                tj[4*q+3] = fmaf(hk, c.w, tj[4*q+3]);
            }
        }
    }
}

__global__ __launch_bounds__(1024, 4) void k_all(
    const float* __restrict__ x,
    const float* __restrict__ W1,  const float* __restrict__ b1,
    const float* __restrict__ g1,  const float* __restrict__ beta1,
    const float* __restrict__ We1, const float* __restrict__ be1,
    const float* __restrict__ ge1, const float* __restrict__ bte1,
    const float* __restrict__ We2, const float* __restrict__ be2,
    const float* __restrict__ ge2, const float* __restrict__ bte2,
    const float* __restrict__ Wg1, const float* __restrict__ bg1,
    const float* __restrict__ Wg2, const float* __restrict__ bg2,
    float* __restrict__ out)
{
    __shared__ __align__(16) float Hs[NN * SROW];   // 69,632 B; also transpose scratch
    __shared__ __align__(16) float PTmax[4][DD], PTmin[4][DD];
    __shared__ __align__(16) float RM[DD], RMn[DD];
    __shared__ __align__(16) float PS[4][DD], PM[4][DD];
    __shared__ __align__(16) float xg[2 * DD];
    __shared__ __align__(16) float hid[DD];

    const int b   = blockIdx.x;
    const int l   = threadIdx.x & 63;                                 // node lane
    const int w   = __builtin_amdgcn_readfirstlane(threadIdx.x >> 6); // wave 0..15
    const int ng  = w >> 2;           // node-group 0..3
    const int d0  = (w & 3) * 16;     // wave-uniform dim slice
    const int n   = ng * 64 + l;      // this thread's node
    const int jd  = l >> 2;           // transpose-read: my dim index (0..15)
    const int cq  = l & 3;            // transpose-read: my node-chunk (0..3)
    float* Ts     = Hs + w * (64 * TPAD);   // per-wave 64x17 scratch

    int voff = 0;
    asm volatile("" : "+v"(voff));    // runtime-0, VGPR-resident: defeats
                                      // uniformity analysis -> VMEM weight loads

    // ================= P0: layer 1 -> Hs rows =================
    {
        float4 xv = *(const float4*)(x + ((size_t)b * NN + n) * 4);
#pragma unroll
        for (int q = 0; q < 4; ++q) {
            float hq[4];
#pragma unroll
            for (int u = 0; u < 4; ++u) {
                const int d = d0 + 4 * q + u;
                float a = b1[d];
                a = fmaf(xv.x, W1[0 * DD + d], a);
                a = fmaf(xv.y, W1[1 * DD + d], a);
                a = fmaf(xv.z, W1[2 * DD + d], a);
                a = fmaf(xv.w, W1[3 * DD + d], a);
                hq[u] = g1[d] * fmaxf(a, 0.f) + beta1[d];
            }
            *(float4*)(Hs + (size_t)n * SROW + d0 + 4 * q) =
                make_float4(hq[0], hq[1], hq[2], hq[3]);
        }
    }
    __syncthreads();

    float ti[16], tj[16];

    // ================= conv1 =================
    conv_full(Hs, n, d0, We1, voff, ti, tj);
    __syncthreads();                       // Hs reads done -> scratch reuse ok

    // tj -> transpose scratch
#pragma unroll
    for (int j = 0; j < 16; ++j) Ts[l * TPAD + j] = tj[j];
    __syncthreads();

    // column reduce: 16 in-lane + 4 shuffles
    {
        float mx = -FMAXV, mn = FMAXV;
#pragma unroll
        for (int r = 0; r < 16; ++r) {
            float v = Ts[(cq * 16 + r) * TPAD + jd];
            mx = fmaxf(mx, v); mn = fminf(mn, v);
        }
        mx = fmaxf(mx, __shfl_xor(mx, 1, 64));
        mx = fmaxf(mx, __shfl_xor(mx, 2, 64));
        mn = fminf(mn, __shfl_xor(mn, 1, 64));
        mn = fminf(mn, __shfl_xor(mn, 2, 64));
        if (cq == 0) { PTmax[ng][d0 + jd] = mx; PTmin[ng][d0 + jd] = mn; }
    }
    __syncthreads();

    // combine 4 node-groups
    {
        const int t = threadIdx.x;
        if (t < DD)
            RM[t] = fmaxf(fmaxf(PTmax[0][t], PTmax[1][t]),
                          fmaxf(PTmax[2][t], PTmax[3][t]));
        else if (t < 2 * DD) {
            const int d = t - DD;
            RMn[d] = fminf(fminf(PTmin[0][d], PTmin[1][d]),
                           fminf(PTmin[2][d], PTmin[3][d]));
        }
    }
    __syncthreads();

    // conv1 epilogue -> Hs rows (monotone bn o max)
    {
#pragma unroll
        for (int q = 0; q < 4; ++q) {
            float4 rmx = *(const float4*)(&RM[d0 + 4 * q]);    // broadcast
            float4 rmn = *(const float4*)(&RMn[d0 + 4 * q]);   // broadcast
            const float rmax[4] = {rmx.x, rmx.y, rmx.z, rmx.w};
            const float rmin[4] = {rmn.x, rmn.y, rmn.z, rmn.w};
            float hq[4];
#pragma unroll
            for (int u = 0; u < 4; ++u) {
                const int d = d0 + 4 * q + u;
                const float gv = ge1[d];
                const float sv = ti[4*q+u] + (gv >= 0.f ? rmax[u] : rmin[u]) + be1[d];
                hq[u] = gv * fmaxf(sv, 0.f) + bte1[d];
            }
            *(float4*)(Hs + (size_t)n * SROW + d0 + 4 * q) =
                make_float4(hq[0], hq[1], hq[2], hq[3]);
        }
    }
    __syncthreads();

    // ================= conv2 =================
    conv_full(Hs, n, d0, We2, voff, ti, tj);
    __syncthreads();

#pragma unroll
    for (int j = 0; j < 16; ++j) Ts[l * TPAD + j] = tj[j];
    __syncthreads();

    {
        float mx = -FMAXV, mn = FMAXV;
#pragma unroll
        for (int r = 0; r < 16; ++r) {
            float v = Ts[(cq * 16 + r) * TPAD + jd];
            mx = fmaxf(mx, v); mn = fminf(mn, v);
        }
        mx = fmaxf(mx, __shfl_xor(mx, 1, 64));
        mx = fmaxf(mx, __shfl_xor(mx, 2, 64));
        mn = fminf(mn, __shfl_xor(mn, 1, 64));
        mn = fminf(mn, __shfl_xor(mn, 2, 64));
        if (cq == 0) { PTmax[ng][d0 + jd] = mx; PTmin[ng][d0 + jd] = mn; }
    }
    __syncthreads();

    {
        const int t = threadIdx.x;
        if (t < DD)
            RM[t] = fmaxf(fmaxf(PTmax[0][t], PTmax[1][t]),
                          fmaxf(PTmax[2][t], PTmax[3][t]));
        else if (t < 2 * DD) {
            const int d = t - DD;
            RMn[d] = fminf(fminf(PTmin[0][d], PTmin[1][d]),
                           fminf(PTmin[2][d], PTmin[3][d]));
        }
    }
    __syncthreads();

    // conv2 epilogue -> h3, into transpose scratch for pooling
    {
#pragma unroll
        for (int q = 0; q < 4; ++q) {
            float4 rmx = *(const float4*)(&RM[d0 + 4 * q]);
            float4 rmn = *(const float4*)(&RMn[d0 + 4 * q]);
            const float rmax[4] = {rmx.x, rmx.y, rmx.z, rmx.w};
            const float rmin[4] = {rmn.x, rmn.y, rmn.z, rmn.w};
#pragma unroll
            for (int u = 0; u < 4; ++u) {
                const int d = d0 + 4 * q + u;
                const float gv = ge2[d];
                const float sv = ti[4*q+u] + (gv >= 0.f ? rmax[u] : rmin[u]) + be2[d];
                Ts[l * TPAD + 4 * q + u] = gv * fmaxf(sv, 0.f) + bte2[d];
            }
        }
    }
    __syncthreads();

    // pooling: column reduce sum & max
    {
        float s = 0.f, mx = -FMAXV;
#pragma unroll
        for (int r = 0; r < 16; ++r) {
            float v = Ts[(cq * 16 + r) * TPAD + jd];
            s += v; mx = fmaxf(mx, v);
        }
        s += __shfl_xor(s, 1, 64);
        s += __shfl_xor(s, 2, 64);
        mx = fmaxf(mx, __shfl_xor(mx, 1, 64));
        mx = fmaxf(mx, __shfl_xor(mx, 2, 64));
        if (cq == 0) { PS[ng][d0 + jd] = s; PM[ng][d0 + jd] = mx; }
    }
    __syncthreads();

    // pooling finalize + head MLP
    const int t = threadIdx.x;
    if (t < DD) {
        xg[t] = (PS[0][t] + PS[1][t] + PS[2][t] + PS[3][t]) * (1.f / 256.f);
    } else if (t < 2 * DD) {
        const int d = t - DD;
        xg[t] = fmaxf(fmaxf(PM[0][d], PM[1][d]), fmaxf(PM[2][d], PM[3][d]));
    }
    __syncthreads();
    if (t < DD) {
        float a = bg1[t];
#pragma unroll
        for (int k = 0; k < 2 * DD; ++k) a = fmaf(xg[k], Wg1[k * DD + t], a);
        hid[t] = fmaxf(a, 0.f);
    }
    __syncthreads();
    if (t < 2) {
        float o = bg2[t];
#pragma unroll
        for (int j = 0; j < DD; ++j) o = fmaf(hid[j], Wg2[j * 2 + t], o);
        out[b * 2 + t] = o;
    }
}

extern "C" void kernel_launch(void* const* d_in, const int* in_sizes, int n_in,
                              void* d_out, int out_size, void* d_ws, size_t ws_size,
                              hipStream_t stream) {
    const float* x     = (const float*)d_in[0];
    const float* W1    = (const float*)d_in[1];
    const float* b1    = (const float*)d_in[2];
    const float* g1    = (const float*)d_in[3];
    const float* beta1 = (const float*)d_in[4];
    const float* We1   = (const float*)d_in[5];
    const float* be1   = (const float*)d_in[6];
    const float* ge1   = (const float*)d_in[7];
    const float* bte1  = (const float*)d_in[8];
    const float* We2   = (const float*)d_in[9];
    const float* be2   = (const float*)d_in[10];
    const float* ge2   = (const float*)d_in[11];
    const float* bte2  = (const float*)d_in[12];
    const float* Wg1   = (const float*)d_in[13];
    const float* bg1   = (const float*)d_in[14];
    const float* Wg2   = (const float*)d_in[15];
    const float* bg2   = (const float*)d_in[16];

    k_all<<<dim3(NB), dim3(1024), 0, stream>>>(
        x, W1, b1, g1, beta1,
        We1, be1, ge1, bte1,
        We2, be2, ge2, bte2,
        Wg1, bg1, Wg2, bg2, (float*)d_out);
}

// Round 11
// 120.414 us; speedup vs baseline: 1.8246x; 1.8246x over previous
//
#include <hip/hip_runtime.h>

#define NB 32
#define NN 256
#define DD 64
#define SROW 68          // LDS row stride (floats); b128-friendly, ~0 conflicts measured
#define TPAD 17          // transpose scratch row stride
#define FMAXV 3.402823466e+38f

// R17: 2 dispatches. R13 (single dispatch, 117.5) spent 39.6us on a 32-CU
// kernel; half of that (conv1) has no cross-node dependency until its
// tj-max and can run FULL-CHIP. R14-R16 proved the per-k s_load drain
// (~64 x 120cyc/conv) can't be fixed at HIP level (SMEM completes
// out-of-order -> only lgkmcnt(0) is safe -> compiler full-drains per k;
// VMEM variant R16 = 150us spill disaster). So divide the stall across
// 8x more CUs instead:
//   k1: 256 blocks x 512 (proven R12 shape): redundant per-thread layer-1
//       (no LDS, no barrier), conv1 matvec, 64-lane tj butterfly ->
//       TI1 + per-group PMAX/PMIN partials. ~4-6us wall.
//   k2: 32 blocks x 1024 (R13 machinery minus conv1): conv1 epilogue ->
//       Hs, conv2 matvec (ti in regs), LDS-transpose tj reduce, conv2
//       epilogue, pooling, head. ~21-25us.
// Cross-block barrier = kernel boundary (R7/R8: any device-scope sync
// primitive costs 25-70us; dispatch boundary is the only cheap one).
// Ascending-k accumulation order preserved everywhere (absmax 0.0 so far).
// ws: TI1 @0 (524288 floats) | PMAX1 @524288 (8192) | PMIN1 @532480 (8192)

__global__ __launch_bounds__(512, 2) void k1_conv(
    const float* __restrict__ x,
    const float* __restrict__ W1,  const float* __restrict__ b1,
    const float* __restrict__ g1,  const float* __restrict__ beta1,
    const float* __restrict__ We1,
    float* __restrict__ TI, float* __restrict__ PMAX, float* __restrict__ PMIN)
{
    const int blk = blockIdx.x;
    const int b   = blk >> 3;
    const int g   = (blk >> 1) & 3;
    const int dh  = blk & 1;
    const int l   = threadIdx.x & 63;                                 // node lane
    const int w   = __builtin_amdgcn_readfirstlane(threadIdx.x >> 6); // wave 0..7
    const int n   = g * 64 + l;
    const int d0  = dh * 32 + w * 4;                                  // wave-uniform

    // full layer-1 row for node n, in registers (redundant across the 16
    // threads covering this node; barrier-free, LDS-free)
    float h[DD];
    {
        float4 xv = *(const float4*)(x + ((size_t)b * NN + n) * 4);
#pragma unroll
        for (int j = 0; j < DD; ++j) {
            float a = b1[j];
            a = fmaf(xv.x, W1[0 * DD + j], a);
            a = fmaf(xv.y, W1[1 * DD + j], a);
            a = fmaf(xv.z, W1[2 * DD + j], a);
            a = fmaf(xv.w, W1[3 * DD + j], a);
            h[j] = g1[j] * fmaxf(a, 0.f) + beta1[j];
        }
    }

    // conv1 matvec: pure s_load(weights)+FMA, h in regs
    float ti[4] = {0.f, 0.f, 0.f, 0.f}, tj[4] = {0.f, 0.f, 0.f, 0.f};
#pragma unroll
    for (int k = 0; k < DD; ++k) {
        const float* wi = We1 + k * DD + d0;          // wave-uniform -> s_load
        const float* wj = We1 + (DD + k) * DD + d0;   // wave-uniform -> s_load
#pragma unroll
        for (int j = 0; j < 4; ++j) {
            ti[j] = fmaf(h[k], wi[j], ti[j]);
            tj[j] = fmaf(h[k], wj[j], tj[j]);
        }
    }
    *(float4*)(TI + ((size_t)(b * NN + n)) * DD + d0) =
        make_float4(ti[0], ti[1], ti[2], ti[3]);

    // tj max/min over this block's 64 nodes
    float mx[4], mn[4];
#pragma unroll
    for (int j = 0; j < 4; ++j) { mx[j] = tj[j]; mn[j] = tj[j]; }
#pragma unroll
    for (int m = 1; m < 64; m <<= 1) {
#pragma unroll
        for (int j = 0; j < 4; ++j) {
            mx[j] = fmaxf(mx[j], __shfl_xor(mx[j], m, 64));
            mn[j] = fminf(mn[j], __shfl_xor(mn[j], m, 64));
        }
    }
    float smx = mx[0], smn = mn[0];
#pragma unroll
    for (int j = 1; j < 4; ++j) {
        smx = (l == j) ? mx[j] : smx;
        smn = (l == j) ? mn[j] : smn;
    }
    if (l < 4) {
        PMAX[(b * 4 + g) * DD + d0 + l] = smx;
        PMIN[(b * 4 + g) * DD + d0 + l] = smn;
    }
}

__device__ __forceinline__ void conv_full(
    const float* Hs, int n, int d0, const float* __restrict__ We,
    float ti[16], float tj[16])
{
#pragma unroll
    for (int j = 0; j < 16; ++j) { ti[j] = 0.f; tj[j] = 0.f; }
    const float* hrow = Hs + (size_t)n * SROW;
#pragma unroll 1
    for (int kc = 0; kc < 4; ++kc) {           // rolled: I$-sized
        float h[16];
#pragma unroll
        for (int q = 0; q < 4; ++q) {
            float4 hv = *(const float4*)(hrow + kc * 16 + 4 * q);
            h[4*q+0] = hv.x; h[4*q+1] = hv.y; h[4*q+2] = hv.z; h[4*q+3] = hv.w;
        }
#pragma unroll
        for (int q = 0; q < 16; ++q) asm volatile("" : "+v"(h[q]));  // pin
#pragma unroll
        for (int kk = 0; kk < 16; ++kk) {      // static h[] index
            const float hk = h[kk];
            const float* wi = We + (size_t)(kc * 16 + kk) * DD + d0;        // uniform
            const float* wj = We + (size_t)(DD + kc * 16 + kk) * DD + d0;   // uniform
#pragma unroll
            for (int q = 0; q < 4; ++q) {
                float4 a = *(const float4*)(wi + 4 * q);
                float4 c = *(const float4*)(wj + 4 * q);
                ti[4*q+0] = fmaf(hk, a.x, ti[4*q+0]);
                ti[4*q+1] = fmaf(hk, a.y, ti[4*q+1]);
                ti[4*q+2] = fmaf(hk, a.z, ti[4*q+2]);
                ti[4*q+3] = fmaf(hk, a.w, ti[4*q+3]);
                tj[4*q+0] = fmaf(hk, c.x, tj[4*q+0]);
                tj[4*q+1] = fmaf(hk, c.y, tj[4*q+1]);
                tj[4*q+2] = fmaf(hk, c.z, tj[4*q+2]);
                tj[4*q+3] = fmaf(hk, c.w, tj[4*q+3]);
            }
        }
    }
}

__global__ __launch_bounds__(1024, 4) void k2_rest(
    const float* __restrict__ PMAXin, const float* __restrict__ PMINin,
    const float* __restrict__ be1P, const float* __restrict__ ge1P,
    const float* __restrict__ bte1P,
    const float* __restrict__ We2, const float* __restrict__ TIin,
    const float* __restrict__ be2P, const float* __restrict__ ge2P,
    const float* __restrict__ bte2P,
    const float* __restrict__ Wg1, const float* __restrict__ bg1,
    const float* __restrict__ Wg2, const float* __restrict__ bg2,
    float* __restrict__ out)
{
    __shared__ __align__(16) float Hs[NN * SROW];   // 69,632 B; also transpose scratch
    __shared__ __align__(16) float PTmax[4][DD], PTmin[4][DD];
    __shared__ __align__(16) float RM[DD], RMn[DD];
    __shared__ __align__(16) float PS[4][DD], PM[4][DD];
    __shared__ __align__(16) float xg[2 * DD];
    __shared__ __align__(16) float hid[DD];

    const int b   = blockIdx.x;
    const int l   = threadIdx.x & 63;                                 // node lane
    const int w   = __builtin_amdgcn_readfirstlane(threadIdx.x >> 6); // wave 0..15
    const int ng  = w >> 2;           // node-group 0..3
    const int d0  = (w & 3) * 16;     // wave-uniform dim slice
    const int n   = ng * 64 + l;      // this thread's node
    const int jd  = l >> 2;           // transpose-read: my dim index (0..15)
    const int cq  = l & 3;            // transpose-read: my node-chunk (0..3)
    float* Ts     = Hs + w * (64 * TPAD);   // per-wave 64x17 scratch

    // ===== conv1 epilogue: combine partials, h2 -> Hs rows =====
    {
        float rmx[16], rmn[16];
#pragma unroll
        for (int q = 0; q < 4; ++q) {
            const int dq = d0 + 4 * q;
            float4 a0 = *(const float4*)(PMAXin + (b * 4 + 0) * DD + dq);
            float4 a1 = *(const float4*)(PMAXin + (b * 4 + 1) * DD + dq);
            float4 a2 = *(const float4*)(PMAXin + (b * 4 + 2) * DD + dq);
            float4 a3 = *(const float4*)(PMAXin + (b * 4 + 3) * DD + dq);
            rmx[4*q+0] = fmaxf(fmaxf(a0.x, a1.x), fmaxf(a2.x, a3.x));
            rmx[4*q+1] = fmaxf(fmaxf(a0.y, a1.y), fmaxf(a2.y, a3.y));
            rmx[4*q+2] = fmaxf(fmaxf(a0.z, a1.z), fmaxf(a2.z, a3.z));
            rmx[4*q+3] = fmaxf(fmaxf(a0.w, a1.w), fmaxf(a2.w, a3.w));
            float4 i0 = *(const float4*)(PMINin + (b * 4 + 0) * DD + dq);
            float4 i1 = *(const float4*)(PMINin + (b * 4 + 1) * DD + dq);
            float4 i2 = *(const float4*)(PMINin + (b * 4 + 2) * DD + dq);
            float4 i3 = *(const float4*)(PMINin + (b * 4 + 3) * DD + dq);
            rmn[4*q+0] = fminf(fminf(i0.x, i1.x), fminf(i2.x, i3.x));
            rmn[4*q+1] = fminf(fminf(i0.y, i1.y), fminf(i2.y, i3.y));
            rmn[4*q+2] = fminf(fminf(i0.z, i1.z), fminf(i2.z, i3.z));
            rmn[4*q+3] = fminf(fminf(i0.w, i1.w), fminf(i2.w, i3.w));
        }
        const float* tip = TIin + ((size_t)(b * NN + n)) * DD + d0;
#pragma unroll
        for (int q = 0; q < 4; ++q) {
            float4 t = *(const float4*)(tip + 4 * q);
            const float tv[4] = {t.x, t.y, t.z, t.w};
            float hq[4];
#pragma unroll
            for (int u = 0; u < 4; ++u) {
                const int d = d0 + 4 * q + u;
                const float gv = ge1P[d];
                const float sv = tv[u] + (gv >= 0.f ? rmx[4*q+u] : rmn[4*q+u]) + be1P[d];
                hq[u] = gv * fmaxf(sv, 0.f) + bte1P[d];
            }
            *(float4*)(Hs + (size_t)n * SROW + d0 + 4 * q) =
                make_float4(hq[0], hq[1], hq[2], hq[3]);
        }
    }
    __syncthreads();

    // ===== conv2 matvec (ti stays in registers) =====
    float ti[16], tj[16];
    conv_full(Hs, n, d0, We2, ti, tj);
    __syncthreads();                       // Hs reads done -> scratch reuse ok

    // tj -> transpose scratch
#pragma unroll
    for (int j = 0; j < 16; ++j) Ts[l * TPAD + j] = tj[j];
    __syncthreads();

    // column reduce: 16 in-lane + 4 shuffles
    {
        float mx = -FMAXV, mn = FMAXV;
#pragma unroll
        for (int r = 0; r < 16; ++r) {
            float v = Ts[(cq * 16 + r) * TPAD + jd];
            mx = fmaxf(mx, v); mn = fminf(mn, v);
        }
        mx = fmaxf(mx, __shfl_xor(mx, 1, 64));
        mx = fmaxf(mx, __shfl_xor(mx, 2, 64));
        mn = fminf(mn, __shfl_xor(mn, 1, 64));
        mn = fminf(mn, __shfl_xor(mn, 2, 64));
        if (cq == 0) { PTmax[ng][d0 + jd] = mx; PTmin[ng][d0 + jd] = mn; }
    }
    __syncthreads();

    // combine 4 node-groups
    {
        const int t = threadIdx.x;
        if (t < DD)
            RM[t] = fmaxf(fmaxf(PTmax[0][t], PTmax[1][t]),
                          fmaxf(PTmax[2][t], PTmax[3][t]));
        else if (t < 2 * DD) {
            const int d = t - DD;
            RMn[d] = fminf(fminf(PTmin[0][d], PTmin[1][d]),
                           fminf(PTmin[2][d], PTmin[3][d]));
        }
    }
    __syncthreads();

    // conv2 epilogue -> h3, into transpose scratch for pooling
    {
#pragma unroll
        for (int q = 0; q < 4; ++q) {
            float4 rmx4 = *(const float4*)(&RM[d0 + 4 * q]);
            float4 rmn4 = *(const float4*)(&RMn[d0 + 4 * q]);
            const float rmax[4] = {rmx4.x, rmx4.y, rmx4.z, rmx4.w};
            const float rmin[4] = {rmn4.x, rmn4.y, rmn4.z, rmn4.w};
#pragma unroll
            for (int u = 0; u < 4; ++u) {
                const int d = d0 + 4 * q + u;
                const float gv = ge2P[d];
                const float sv = ti[4*q+u] + (gv >= 0.f ? rmax[u] : rmin[u]) + be2P[d];
                Ts[l * TPAD + 4 * q + u] = gv * fmaxf(sv, 0.f) + bte2P[d];
            }
        }
    }
    __syncthreads();

    // pooling: column reduce sum & max
    {
        float s = 0.f, mx = -FMAXV;
#pragma unroll
        for (int r = 0; r < 16; ++r) {
            float v = Ts[(cq * 16 + r) * TPAD + jd];
            s += v; mx = fmaxf(mx, v);
        }
        s += __shfl_xor(s, 1, 64);
        s += __shfl_xor(s, 2, 64);
        mx = fmaxf(mx, __shfl_xor(mx, 1, 64));
        mx = fmaxf(mx, __shfl_xor(mx, 2, 64));
        if (cq == 0) { PS[ng][d0 + jd] = s; PM[ng][d0 + jd] = mx; }
    }
    __syncthreads();

    // pooling finalize + head MLP
    const int t = threadIdx.x;
    if (t < DD) {
        xg[t] = (PS[0][t] + PS[1][t] + PS[2][t] + PS[3][t]) * (1.f / 256.f);
    } else if (t < 2 * DD) {
        const int d = t - DD;
        xg[t] = fmaxf(fmaxf(PM[0][d], PM[1][d]), fmaxf(PM[2][d], PM[3][d]));
    }
    __syncthreads();
    if (t < DD) {
        float a = bg1[t];
#pragma unroll
        for (int k = 0; k < 2 * DD; ++k) a = fmaf(xg[k], Wg1[k * DD + t], a);
        hid[t] = fmaxf(a, 0.f);
    }
    __syncthreads();
    if (t < 2) {
        float o = bg2[t];
#pragma unroll
        for (int j = 0; j < DD; ++j) o = fmaf(hid[j], Wg2[j * 2 + t], o);
        out[b * 2 + t] = o;
    }
}

extern "C" void kernel_launch(void* const* d_in, const int* in_sizes, int n_in,
                              void* d_out, int out_size, void* d_ws, size_t ws_size,
                              hipStream_t stream) {
    const float* x     = (const float*)d_in[0];
    const float* W1    = (const float*)d_in[1];
    const float* b1    = (const float*)d_in[2];
    const float* g1    = (const float*)d_in[3];
    const float* beta1 = (const float*)d_in[4];
    const float* We1   = (const float*)d_in[5];
    const float* be1   = (const float*)d_in[6];
    const float* ge1   = (const float*)d_in[7];
    const float* bte1  = (const float*)d_in[8];
    const float* We2   = (const float*)d_in[9];
    const float* be2   = (const float*)d_in[10];
    const float* ge2   = (const float*)d_in[11];
    const float* bte2  = (const float*)d_in[12];
    const float* Wg1   = (const float*)d_in[13];
    const float* bg1   = (const float*)d_in[14];
    const float* Wg2   = (const float*)d_in[15];
    const float* bg2   = (const float*)d_in[16];

    float* ws    = (float*)d_ws;
    float* TI1   = ws;
    float* PMAX1 = ws + 524288;
    float* PMIN1 = ws + 532480;

    k1_conv<<<dim3(NB * 8), dim3(512), 0, stream>>>(
        x, W1, b1, g1, beta1, We1, TI1, PMAX1, PMIN1);
    k2_rest<<<dim3(NB), dim3(1024), 0, stream>>>(
        PMAX1, PMIN1, be1, ge1, bte1, We2, TI1,
        be2, ge2, bte2, Wg1, bg1, Wg2, bg2, (float*)d_out);
}